// Round 5
// baseline (1824.706 us; speedup 1.0000x reference)
//
#include <hip/hip_runtime.h>

typedef _Float16 f16;
typedef _Float16 f16x2 __attribute__((ext_vector_type(2)));
typedef _Float16 f16x8 __attribute__((ext_vector_type(8)));
typedef float f32x4 __attribute__((ext_vector_type(4)));
typedef unsigned int u32;

#define SEQ   512
#define BATCH 256
#define INS   58
#define INP   64          // padded input width
#define HID   256
#define NCAT  18
#define G3    (3*HID)     // 768
#define TC    128         // timestep chunk
#define NCHUNK (SEQ/TC)   // 4
#define MC    (TC*BATCH)  // 32768 rows per chunk
#define HPAD  8           // f16 pad between K-halves (272B -> +4 banks)
#define HLD   (HID + HPAD)

// ---------------------------------------------------------------- dot2 helper
__device__ __forceinline__ float fdot2f(u32 a, u32 b, float c) {
#if __has_builtin(__builtin_amdgcn_fdot2)
  return __builtin_amdgcn_fdot2(__builtin_bit_cast(f16x2, a),
                                __builtin_bit_cast(f16x2, b), c, false);
#else
  f16x2 av = __builtin_bit_cast(f16x2, a);
  f16x2 bv = __builtin_bit_cast(f16x2, b);
  return c + (float)av[0] * (float)bv[0] + (float)av[1] * (float)bv[1];
#endif
}

// ------------------------------------------------------- f32 -> f16 (pad cols)
__global__ void k_convert_pad(const float* __restrict__ src, f16* __restrict__ dst,
                              int rows, int scols, int dcols) {
  int i = blockIdx.x * blockDim.x + threadIdx.x;
  int total = rows * dcols;
  if (i >= total) return;
  int r = i / dcols, c = i - r * dcols;
  float v = (c < scols) ? src[(size_t)r * scols + c] : 0.f;
  dst[i] = (f16)v;
}

// --------------------------------------------------------------- f16 MFMA GEMM
// out[M][768] = A[M][K] * W[768][K]^T + bias.  128x128 tile, BK=32, 4 waves.
#define BM 128
#define BN 128
#define BK 32
#define LDP 40   // padded LDS pitch (f16 elems)

__global__ __launch_bounds__(256, 2)
void k_gemm_f16(const f16* __restrict__ A, const f16* __restrict__ W,
                const float* __restrict__ bias, f16* __restrict__ out,
                int K) {
  __shared__ __align__(16) f16 As[BM][LDP];
  __shared__ __align__(16) f16 Ws[BN][LDP];
  const int tid  = threadIdx.x;
  const int lane = tid & 63;
  const int wave = tid >> 6;            // 0..3
  const int wm = wave >> 1, wn = wave & 1;
  const int n0 = blockIdx.x * BN;       // grid.x = 6
  const int m0 = blockIdx.y * BM;       // grid.y = MC/BM

  f32x4 acc[4][4] = {};

  for (int k0 = 0; k0 < K; k0 += BK) {
    __syncthreads();
#pragma unroll
    for (int c = 0; c < 2; ++c) {
      int j   = c * 256 + tid;          // 0..511
      int row = j >> 2;                 // 0..127
      int kc  = j & 3;                  // 16B chunk within 32-col row
      uint4 va = *(const uint4*)(A + (size_t)(m0 + row) * K + k0 + kc * 8);
      *(uint4*)(&As[row][kc * 8]) = va;
      uint4 vw = *(const uint4*)(W + (size_t)(n0 + row) * K + k0 + kc * 8);
      *(uint4*)(&Ws[row][kc * 8]) = vw;
    }
    __syncthreads();
    const int rsel = lane & 15;
    const int ks   = (lane >> 4) * 8;
    f16x8 af[4], bf[4];
#pragma unroll
    for (int i = 0; i < 4; ++i)
      af[i] = *(const f16x8*)(&As[wm * 64 + i * 16 + rsel][ks]);
#pragma unroll
    for (int j = 0; j < 4; ++j)
      bf[j] = *(const f16x8*)(&Ws[wn * 64 + j * 16 + rsel][ks]);
#pragma unroll
    for (int i = 0; i < 4; ++i)
#pragma unroll
      for (int j = 0; j < 4; ++j)
        acc[i][j] = __builtin_amdgcn_mfma_f32_16x16x32_f16(af[i], bf[j], acc[i][j], 0, 0, 0);
  }

#pragma unroll
  for (int j = 0; j < 4; ++j) {
    int col = n0 + wn * 64 + j * 16 + (lane & 15);
    float bv = bias[col];
#pragma unroll
    for (int i = 0; i < 4; ++i) {
      int rbase = m0 + wm * 64 + i * 16 + ((lane >> 4) << 2);
#pragma unroll
      for (int rr = 0; rr < 4; ++rr)
        out[(size_t)(rbase + rr) * G3 + col] = (f16)(acc[i][j][rr] + bv);
    }
  }
}

// ------------------------------------------------------ persistent GRU layer
// One workgroup (512 threads, 2 waves/EU -> 256-VGPR budget) per batch element.
// Thread pair (2r, 2r+1) owns hidden unit r: even lane K-cols [0,128), odd
// [128,256), gate rows {r, 256+r, 512+r}. Weights pinned resident in VGPRs by
// re-pinning INSIDE the loop (spill would cost store+reload per step).
// h double-buffered in LDS, +8 f16 pad between halves. ONE barrier per step.
template <int FINAL>
__global__ __attribute__((amdgpu_flat_work_group_size(512, 512),
                          amdgpu_waves_per_eu(2, 2)))
void k_gru(const f16* __restrict__ gx,     // [MC][768], includes b_ih
           const f16* __restrict__ Whh,    // [768][256] f16
           const float* __restrict__ bhh,  // [768]
           f16* __restrict__ hout,         // [MC][256]   (FINAL==0)
           float* __restrict__ hstate,     // [BATCH][256] f32 carry
           int first, int last,
           const float* __restrict__ fcw,  // [18][256]  (FINAL only)
           const float* __restrict__ fcb,  // [18]
           float* __restrict__ out) {      // [256][18]
  const int b   = blockIdx.x;
  const int tid = threadIdx.x;
  const int r   = tid >> 1;   // hidden index 0..255
  const int kh  = tid & 1;    // K half

  __shared__ __align__(16) f16 hsh[2][HLD];
  __shared__ float red[HID];
  __shared__ float red2[NCAT * 16];

  // ---- load recurrent weights into registers (192 VGPRs of packed f16) ----
  u32 w0[64], w1[64], w2[64];
  {
    const f16* base = Whh + (size_t)kh * 128;
#pragma unroll
    for (int c = 0; c < 16; ++c) {
      uint4 v0 = *(const uint4*)(base + (size_t)(0 * HID + r) * HID + c * 8);
      w0[c * 4 + 0] = v0.x; w0[c * 4 + 1] = v0.y; w0[c * 4 + 2] = v0.z; w0[c * 4 + 3] = v0.w;
      uint4 v1 = *(const uint4*)(base + (size_t)(1 * HID + r) * HID + c * 8);
      w1[c * 4 + 0] = v1.x; w1[c * 4 + 1] = v1.y; w1[c * 4 + 2] = v1.z; w1[c * 4 + 3] = v1.w;
      uint4 v2 = *(const uint4*)(base + (size_t)(2 * HID + r) * HID + c * 8);
      w2[c * 4 + 0] = v2.x; w2[c * 4 + 1] = v2.y; w2[c * 4 + 2] = v2.z; w2[c * 4 + 3] = v2.w;
    }
  }

  float bhr = 0.f, bhz = 0.f, bhn = 0.f;
  float hprev = 0.f;
  if (kh == 0) {
    bhr = bhh[r]; bhz = bhh[HID + r]; bhn = bhh[2 * HID + r];
    hprev = first ? 0.f : hstate[(size_t)b * HID + r];
    hsh[0][r + (r >= 128 ? HPAD : 0)] = (f16)hprev;
  }

  // prefetch gx for t=0
  float gxr = 0.f, gxz = 0.f, gxn = 0.f;
  if (kh == 0) {
    const f16* g0 = gx + ((size_t)0 * BATCH + b) * G3;
    gxr = (float)g0[r]; gxz = (float)g0[HID + r]; gxn = (float)g0[2 * HID + r];
  }
  __syncthreads();

  int cur = 0;
  for (int t = 0; t < TC; ++t) {
    // re-pin weights EVERY iteration: spilling now costs a per-step
    // store+reload, so the allocator keeps all 192 values resident.
#pragma unroll
    for (int i = 0; i < 64; ++i)
      asm volatile("" : "+v"(w0[i]), "+v"(w1[i]), "+v"(w2[i]));

    // prefetch next timestep's gx (consumed after the dot phase)
    float nxr = 0.f, nxz = 0.f, nxn = 0.f;
    if (kh == 0 && t + 1 < TC) {
      const f16* gn = gx + ((size_t)(t + 1) * BATCH + b) * G3;
      nxr = (float)gn[r]; nxz = (float)gn[HID + r]; nxn = (float)gn[2 * HID + r];
    }

    // ---- dot phase over this lane's K half (broadcast reads, padded) ----
    float ar = 0.f, az = 0.f, an = 0.f;
    const uint4* hp = (const uint4*)(&hsh[cur][kh * (128 + HPAD)]);
#pragma unroll
    for (int c = 0; c < 16; ++c) {
      uint4 v = hp[c];
      ar = fdot2f(w0[c * 4 + 0], v.x, ar);
      az = fdot2f(w1[c * 4 + 0], v.x, az);
      an = fdot2f(w2[c * 4 + 0], v.x, an);
      ar = fdot2f(w0[c * 4 + 1], v.y, ar);
      az = fdot2f(w1[c * 4 + 1], v.y, az);
      an = fdot2f(w2[c * 4 + 1], v.y, an);
      ar = fdot2f(w0[c * 4 + 2], v.z, ar);
      az = fdot2f(w1[c * 4 + 2], v.z, az);
      an = fdot2f(w2[c * 4 + 2], v.z, an);
      ar = fdot2f(w0[c * 4 + 3], v.w, ar);
      az = fdot2f(w1[c * 4 + 3], v.w, az);
      an = fdot2f(w2[c * 4 + 3], v.w, an);
    }
    // merge K halves within the lane pair (same wave -> no barrier)
    ar += __shfl_xor(ar, 1);
    az += __shfl_xor(az, 1);
    an += __shfl_xor(an, 1);

    if (kh == 0) {
      float ghr = ar + bhr;
      float ghz = az + bhz;
      float ghn = an + bhn;
      float rg = 1.f / (1.f + __expf(-(gxr + ghr)));
      float zg = 1.f / (1.f + __expf(-(gxz + ghz)));
      float nt = gxn + rg * ghn;
      float e2 = __expf(-2.f * fabsf(nt));       // safe tanh
      float th = (1.f - e2) / (1.f + e2);
      float ng = (nt >= 0.f) ? th : -th;
      float hn = (1.f - zg) * ng + zg * hprev;
      hprev = hn;
      hsh[cur ^ 1][r + (r >= 128 ? HPAD : 0)] = (f16)hn;  // other buffer
      if (!FINAL) hout[((size_t)t * BATCH + b) * HID + r] = (f16)hn;
      gxr = nxr; gxz = nxz; gxn = nxn;
    }
    __syncthreads();                             // h_new visible to all
    cur ^= 1;
  }

  if (kh == 0) hstate[(size_t)b * HID + r] = hprev;

  if (FINAL) {
    if (last) {
      if (kh == 0) red[r] = hprev;
      __syncthreads();
      int c = tid >> 4, seg = tid & 15;
      if (c < NCAT) {
        const float* wrow = fcw + (size_t)c * HID + seg * 16;
        const float* hseg = red + seg * 16;
        float s = 0.f;
#pragma unroll
        for (int q = 0; q < 16; ++q) s += wrow[q] * hseg[q];
        red2[c * 16 + seg] = s;
      }
      __syncthreads();
      if (tid < NCAT) {
        float s = fcb[tid];
#pragma unroll
        for (int k = 0; k < 16; ++k) s += red2[tid * 16 + k];
        out[(size_t)b * NCAT + tid] = s;
      }
    }
  }
}

// ---------------------------------------------------------------------- launch
extern "C" void kernel_launch(void* const* d_in, const int* in_sizes, int n_in,
                              void* d_out, int out_size, void* d_ws, size_t ws_size,
                              hipStream_t stream) {
  const float* x    = (const float*)d_in[0];
  const float* Wih0 = (const float*)d_in[1];
  const float* Whh0 = (const float*)d_in[2];
  const float* bih0 = (const float*)d_in[3];
  const float* bhh0 = (const float*)d_in[4];
  const float* Wih1 = (const float*)d_in[5];
  const float* Whh1 = (const float*)d_in[6];
  const float* bih1 = (const float*)d_in[7];
  const float* bhh1 = (const float*)d_in[8];
  const float* fcw  = (const float*)d_in[9];
  const float* fcb  = (const float*)d_in[10];
  float* out = (float*)d_out;

  // ---- workspace layout (~73 MB total) ----
  char* ws = (char*)d_ws;
  size_t off = 0;
  f16*   whh0h = (f16*)(ws + off); off += (size_t)G3 * HID * 2;      //   393,216
  f16*   whh1h = (f16*)(ws + off); off += (size_t)G3 * HID * 2;      //   393,216
  f16*   wih0h = (f16*)(ws + off); off += (size_t)G3 * INP * 2;      //    98,304
  f16*   wih1h = (f16*)(ws + off); off += (size_t)G3 * HID * 2;      //   393,216
  float* h0st  = (float*)(ws + off); off += (size_t)BATCH * HID * 4; //   262,144
  float* h1st  = (float*)(ws + off); off += (size_t)BATCH * HID * 4; //   262,144
  f16*   xhc   = (f16*)(ws + off); off += (size_t)MC * INP * 2;      // 4,194,304
  f16*   h0c   = (f16*)(ws + off); off += (size_t)MC * HID * 2;      // 16,777,216
  f16*   gxc   = (f16*)(ws + off); off += (size_t)MC * G3 * 2;       // 50,331,648
  // total ~73.1 MB

  // ---- one-time weight converts ----
  k_convert_pad<<<(G3 * INP + 255) / 256, 256, 0, stream>>>(Wih0, wih0h, G3, INS, INP);
  k_convert_pad<<<(G3 * HID + 255) / 256, 256, 0, stream>>>(Whh0, whh0h, G3, HID, HID);
  k_convert_pad<<<(G3 * HID + 255) / 256, 256, 0, stream>>>(Whh1, whh1h, G3, HID, HID);
  k_convert_pad<<<(G3 * HID + 255) / 256, 256, 0, stream>>>(Wih1, wih1h, G3, HID, HID);

  for (int c = 0; c < NCHUNK; ++c) {
    int first = (c == 0), last = (c == NCHUNK - 1);
    const float* xc = x + (size_t)c * MC * INS;

    // x chunk -> f16, pad 58 -> 64
    k_convert_pad<<<(MC * INP + 255) / 256, 256, 0, stream>>>(xc, xhc, MC, INS, INP);
    // gx0 = xh @ Wih0^T + b_ih0
    k_gemm_f16<<<dim3(G3 / BN, MC / BM), 256, 0, stream>>>(xhc, wih0h, bih0, gxc, INP);
    // layer-0 recurrence over this chunk
    k_gru<0><<<BATCH, 512, 0, stream>>>(gxc, whh0h, bhh0, h0c, h0st, first, last,
                                        nullptr, nullptr, nullptr);
    // gx1 = h0 @ Wih1^T + b_ih1 (reuse gxc; stream order serializes)
    k_gemm_f16<<<dim3(G3 / BN, MC / BM), 256, 0, stream>>>(h0c, wih1h, bih1, gxc, HID);
    // layer-1 recurrence (+ final FC on last chunk)
    k_gru<1><<<BATCH, 512, 0, stream>>>(gxc, whh1h, bhh1, nullptr, h1st, first, last,
                                        fcw, fcb, out);
  }
}

// Round 6
// 1813.884 us; speedup vs baseline: 1.0060x; 1.0060x over previous
//
#include <hip/hip_runtime.h>

typedef _Float16 f16;
typedef _Float16 f16x2 __attribute__((ext_vector_type(2)));
typedef _Float16 f16x8 __attribute__((ext_vector_type(8)));
typedef float f32x4 __attribute__((ext_vector_type(4)));
typedef unsigned int u32;
typedef u32 u32x16 __attribute__((ext_vector_type(16)));

#define SEQ   512
#define BATCH 256
#define INS   58
#define INP   64          // padded input width
#define HID   256
#define NCAT  18
#define G3    (3*HID)     // 768
#define TC    128         // timestep chunk
#define NCHUNK (SEQ/TC)   // 4
#define MC    (TC*BATCH)  // 32768 rows per chunk
#define HPAD  8           // f16 pad between K-halves (272B -> +4 banks)
#define HLD   (HID + HPAD)

// ---------------------------------------------------------------- dot2 helper
__device__ __forceinline__ float fdot2f(u32 a, u32 b, float c) {
#if __has_builtin(__builtin_amdgcn_fdot2)
  return __builtin_amdgcn_fdot2(__builtin_bit_cast(f16x2, a),
                                __builtin_bit_cast(f16x2, b), c, false);
#else
  f16x2 av = __builtin_bit_cast(f16x2, a);
  f16x2 bv = __builtin_bit_cast(f16x2, b);
  return c + (float)av[0] * (float)bv[0] + (float)av[1] * (float)bv[1];
#endif
}

// ------------------------------------------------------- f32 -> f16 (pad cols)
__global__ void k_convert_pad(const float* __restrict__ src, f16* __restrict__ dst,
                              int rows, int scols, int dcols) {
  int i = blockIdx.x * blockDim.x + threadIdx.x;
  int total = rows * dcols;
  if (i >= total) return;
  int r = i / dcols, c = i - r * dcols;
  float v = (c < scols) ? src[(size_t)r * scols + c] : 0.f;
  dst[i] = (f16)v;
}

// --------------------------------------------------------------- f16 MFMA GEMM
// out[M][768] = A[M][K] * W[768][K]^T + bias.  128x128 tile, BK=32, 4 waves.
#define BM 128
#define BN 128
#define BK 32
#define LDP 40   // padded LDS pitch (f16 elems)

__global__ __launch_bounds__(256, 2)
void k_gemm_f16(const f16* __restrict__ A, const f16* __restrict__ W,
                const float* __restrict__ bias, f16* __restrict__ out,
                int K) {
  __shared__ __align__(16) f16 As[BM][LDP];
  __shared__ __align__(16) f16 Ws[BN][LDP];
  const int tid  = threadIdx.x;
  const int lane = tid & 63;
  const int wave = tid >> 6;            // 0..3
  const int wm = wave >> 1, wn = wave & 1;
  const int n0 = blockIdx.x * BN;       // grid.x = 6
  const int m0 = blockIdx.y * BM;       // grid.y = MC/BM

  f32x4 acc[4][4] = {};

  for (int k0 = 0; k0 < K; k0 += BK) {
    __syncthreads();
#pragma unroll
    for (int c = 0; c < 2; ++c) {
      int j   = c * 256 + tid;          // 0..511
      int row = j >> 2;                 // 0..127
      int kc  = j & 3;                  // 16B chunk within 32-col row
      uint4 va = *(const uint4*)(A + (size_t)(m0 + row) * K + k0 + kc * 8);
      *(uint4*)(&As[row][kc * 8]) = va;
      uint4 vw = *(const uint4*)(W + (size_t)(n0 + row) * K + k0 + kc * 8);
      *(uint4*)(&Ws[row][kc * 8]) = vw;
    }
    __syncthreads();
    const int rsel = lane & 15;
    const int ks   = (lane >> 4) * 8;
    f16x8 af[4], bf[4];
#pragma unroll
    for (int i = 0; i < 4; ++i)
      af[i] = *(const f16x8*)(&As[wm * 64 + i * 16 + rsel][ks]);
#pragma unroll
    for (int j = 0; j < 4; ++j)
      bf[j] = *(const f16x8*)(&Ws[wn * 64 + j * 16 + rsel][ks]);
#pragma unroll
    for (int i = 0; i < 4; ++i)
#pragma unroll
      for (int j = 0; j < 4; ++j)
        acc[i][j] = __builtin_amdgcn_mfma_f32_16x16x32_f16(af[i], bf[j], acc[i][j], 0, 0, 0);
  }

#pragma unroll
  for (int j = 0; j < 4; ++j) {
    int col = n0 + wn * 64 + j * 16 + (lane & 15);
    float bv = bias[col];
#pragma unroll
    for (int i = 0; i < 4; ++i) {
      int rbase = m0 + wm * 64 + i * 16 + ((lane >> 4) << 2);
#pragma unroll
      for (int rr = 0; rr < 4; ++rr)
        out[(size_t)(rbase + rr) * G3 + col] = (f16)(acc[i][j][rr] + bv);
    }
  }
}

// ------------------------------------------------------ persistent GRU layer
// One workgroup (512 threads) per batch element. Thread pair (2r, 2r+1) owns
// hidden unit r: even lane K-cols [0,128), odd [128,256), gate rows
// {r, 256+r, 512+r}. Weights live in 12 x 512-bit vectors (192 VGPRs) pinned
// by a SINGLE asm with all 12 as "+v" operands -> 192 registers must be
// simultaneously live; re-issued each t-iteration so values are asm-carried
// (not rematerializable). h double-buffered in LDS, ONE barrier per step.
#define WV(g, j) wv[(g)*4 + ((j) >> 4)][(j) & 15]
#define PIN_W() asm volatile("" \
    : "+v"(wv[0]), "+v"(wv[1]), "+v"(wv[2]), "+v"(wv[3]), \
      "+v"(wv[4]), "+v"(wv[5]), "+v"(wv[6]), "+v"(wv[7]), \
      "+v"(wv[8]), "+v"(wv[9]), "+v"(wv[10]), "+v"(wv[11]))

template <int FINAL>
__global__ __attribute__((amdgpu_flat_work_group_size(512, 512),
                          amdgpu_waves_per_eu(2, 2)))
void k_gru(const f16* __restrict__ gx,     // [MC][768], includes b_ih
           const f16* __restrict__ Whh,    // [768][256] f16
           const float* __restrict__ bhh,  // [768]
           f16* __restrict__ hout,         // [MC][256]   (FINAL==0)
           float* __restrict__ hstate,     // [BATCH][256] f32 carry
           int first, int last,
           const float* __restrict__ fcw,  // [18][256]  (FINAL only)
           const float* __restrict__ fcb,  // [18]
           float* __restrict__ out) {      // [256][18]
  const int b   = blockIdx.x;
  const int tid = threadIdx.x;
  const int r   = tid >> 1;   // hidden index 0..255
  const int kh  = tid & 1;    // K half

  __shared__ __align__(16) f16 hsh[2][HLD];
  __shared__ float red[HID];
  __shared__ float red2[NCAT * 16];

  // ---- load recurrent weights into 12 x 512-bit register vectors ----
  u32x16 wv[12];
#pragma unroll
  for (int g = 0; g < 3; ++g) {
    const f16* gbase = Whh + (size_t)(g * HID + r) * HID + kh * 128;
#pragma unroll
    for (int c = 0; c < 16; ++c) {              // c-th 16B chunk (8 f16)
      uint4 v = *(const uint4*)(gbase + c * 8);
      wv[g * 4 + (c >> 2)][(c & 3) * 4 + 0] = v.x;
      wv[g * 4 + (c >> 2)][(c & 3) * 4 + 1] = v.y;
      wv[g * 4 + (c >> 2)][(c & 3) * 4 + 2] = v.z;
      wv[g * 4 + (c >> 2)][(c & 3) * 4 + 3] = v.w;
    }
  }
  PIN_W();   // force all 192 weight VGPRs simultaneously live

  float bhr = 0.f, bhz = 0.f, bhn = 0.f;
  float hprev = 0.f;
  if (kh == 0) {
    bhr = bhh[r]; bhz = bhh[HID + r]; bhn = bhh[2 * HID + r];
    hprev = first ? 0.f : hstate[(size_t)b * HID + r];
    hsh[0][r + (r >= 128 ? HPAD : 0)] = (f16)hprev;
  }

  // prefetch gx for t=0
  float gxr = 0.f, gxz = 0.f, gxn = 0.f;
  if (kh == 0) {
    const f16* g0 = gx + ((size_t)0 * BATCH + b) * G3;
    gxr = (float)g0[r]; gxz = (float)g0[HID + r]; gxn = (float)g0[2 * HID + r];
  }
  __syncthreads();

  int cur = 0;
  for (int t = 0; t < TC; ++t) {
    PIN_W();   // asm-carried across iterations: weights cannot be remat'd

    // prefetch next timestep's gx (consumed after the dot phase)
    float nxr = 0.f, nxz = 0.f, nxn = 0.f;
    if (kh == 0 && t + 1 < TC) {
      const f16* gn = gx + ((size_t)(t + 1) * BATCH + b) * G3;
      nxr = (float)gn[r]; nxz = (float)gn[HID + r]; nxn = (float)gn[2 * HID + r];
    }

    // ---- dot phase over this lane's K half (broadcast reads, padded) ----
    float ar = 0.f, az = 0.f, an = 0.f;
    const uint4* hp = (const uint4*)(&hsh[cur][kh * (128 + HPAD)]);
#pragma unroll
    for (int c = 0; c < 16; ++c) {
      uint4 v = hp[c];
      ar = fdot2f(WV(0, c * 4 + 0), v.x, ar);
      az = fdot2f(WV(1, c * 4 + 0), v.x, az);
      an = fdot2f(WV(2, c * 4 + 0), v.x, an);
      ar = fdot2f(WV(0, c * 4 + 1), v.y, ar);
      az = fdot2f(WV(1, c * 4 + 1), v.y, az);
      an = fdot2f(WV(2, c * 4 + 1), v.y, an);
      ar = fdot2f(WV(0, c * 4 + 2), v.z, ar);
      az = fdot2f(WV(1, c * 4 + 2), v.z, az);
      an = fdot2f(WV(2, c * 4 + 2), v.z, an);
      ar = fdot2f(WV(0, c * 4 + 3), v.w, ar);
      az = fdot2f(WV(1, c * 4 + 3), v.w, az);
      an = fdot2f(WV(2, c * 4 + 3), v.w, an);
    }
    // merge K halves within the lane pair (same wave -> no barrier)
    ar += __shfl_xor(ar, 1);
    az += __shfl_xor(az, 1);
    an += __shfl_xor(an, 1);

    if (kh == 0) {
      float ghr = ar + bhr;
      float ghz = az + bhz;
      float ghn = an + bhn;
      float rg = 1.f / (1.f + __expf(-(gxr + ghr)));
      float zg = 1.f / (1.f + __expf(-(gxz + ghz)));
      float nt = gxn + rg * ghn;
      float e2 = __expf(-2.f * fabsf(nt));       // safe tanh
      float th = (1.f - e2) / (1.f + e2);
      float ng = (nt >= 0.f) ? th : -th;
      float hn = (1.f - zg) * ng + zg * hprev;
      hprev = hn;
      hsh[cur ^ 1][r + (r >= 128 ? HPAD : 0)] = (f16)hn;  // other buffer
      if (!FINAL) hout[((size_t)t * BATCH + b) * HID + r] = (f16)hn;
      gxr = nxr; gxz = nxz; gxn = nxn;
    }
    __syncthreads();                             // h_new visible to all
    cur ^= 1;
  }

  if (kh == 0) hstate[(size_t)b * HID + r] = hprev;

  if (FINAL) {
    if (last) {
      if (kh == 0) red[r] = hprev;
      __syncthreads();
      int c = tid >> 4, seg = tid & 15;
      if (c < NCAT) {
        const float* wrow = fcw + (size_t)c * HID + seg * 16;
        const float* hseg = red + seg * 16;
        float s = 0.f;
#pragma unroll
        for (int q = 0; q < 16; ++q) s += wrow[q] * hseg[q];
        red2[c * 16 + seg] = s;
      }
      __syncthreads();
      if (tid < NCAT) {
        float s = fcb[tid];
#pragma unroll
        for (int k = 0; k < 16; ++k) s += red2[tid * 16 + k];
        out[(size_t)b * NCAT + tid] = s;
      }
    }
  }
}

// ---------------------------------------------------------------------- launch
extern "C" void kernel_launch(void* const* d_in, const int* in_sizes, int n_in,
                              void* d_out, int out_size, void* d_ws, size_t ws_size,
                              hipStream_t stream) {
  const float* x    = (const float*)d_in[0];
  const float* Wih0 = (const float*)d_in[1];
  const float* Whh0 = (const float*)d_in[2];
  const float* bih0 = (const float*)d_in[3];
  const float* bhh0 = (const float*)d_in[4];
  const float* Wih1 = (const float*)d_in[5];
  const float* Whh1 = (const float*)d_in[6];
  const float* bih1 = (const float*)d_in[7];
  const float* bhh1 = (const float*)d_in[8];
  const float* fcw  = (const float*)d_in[9];
  const float* fcb  = (const float*)d_in[10];
  float* out = (float*)d_out;

  // ---- workspace layout (~73 MB total) ----
  char* ws = (char*)d_ws;
  size_t off = 0;
  f16*   whh0h = (f16*)(ws + off); off += (size_t)G3 * HID * 2;      //   393,216
  f16*   whh1h = (f16*)(ws + off); off += (size_t)G3 * HID * 2;      //   393,216
  f16*   wih0h = (f16*)(ws + off); off += (size_t)G3 * INP * 2;      //    98,304
  f16*   wih1h = (f16*)(ws + off); off += (size_t)G3 * HID * 2;      //   393,216
  float* h0st  = (float*)(ws + off); off += (size_t)BATCH * HID * 4; //   262,144
  float* h1st  = (float*)(ws + off); off += (size_t)BATCH * HID * 4; //   262,144
  f16*   xhc   = (f16*)(ws + off); off += (size_t)MC * INP * 2;      // 4,194,304
  f16*   h0c   = (f16*)(ws + off); off += (size_t)MC * HID * 2;      // 16,777,216
  f16*   gxc   = (f16*)(ws + off); off += (size_t)MC * G3 * 2;       // 50,331,648
  // total ~73.1 MB

  // ---- one-time weight converts ----
  k_convert_pad<<<(G3 * INP + 255) / 256, 256, 0, stream>>>(Wih0, wih0h, G3, INS, INP);
  k_convert_pad<<<(G3 * HID + 255) / 256, 256, 0, stream>>>(Whh0, whh0h, G3, HID, HID);
  k_convert_pad<<<(G3 * HID + 255) / 256, 256, 0, stream>>>(Whh1, whh1h, G3, HID, HID);
  k_convert_pad<<<(G3 * HID + 255) / 256, 256, 0, stream>>>(Wih1, wih1h, G3, HID, HID);

  for (int c = 0; c < NCHUNK; ++c) {
    int first = (c == 0), last = (c == NCHUNK - 1);
    const float* xc = x + (size_t)c * MC * INS;

    // x chunk -> f16, pad 58 -> 64
    k_convert_pad<<<(MC * INP + 255) / 256, 256, 0, stream>>>(xc, xhc, MC, INS, INP);
    // gx0 = xh @ Wih0^T + b_ih0
    k_gemm_f16<<<dim3(G3 / BN, MC / BM), 256, 0, stream>>>(xhc, wih0h, bih0, gxc, INP);
    // layer-0 recurrence over this chunk
    k_gru<0><<<BATCH, 512, 0, stream>>>(gxc, whh0h, bhh0, h0c, h0st, first, last,
                                        nullptr, nullptr, nullptr);
    // gx1 = h0 @ Wih1^T + b_ih1 (reuse gxc; stream order serializes)
    k_gemm_f16<<<dim3(G3 / BN, MC / BM), 256, 0, stream>>>(h0c, wih1h, bih1, gxc, HID);
    // layer-1 recurrence (+ final FC on last chunk)
    k_gru<1><<<BATCH, 512, 0, stream>>>(gxc, whh1h, bhh1, nullptr, h1st, first, last,
                                        fcw, fcb, out);
  }
}

// Round 7
// 1787.695 us; speedup vs baseline: 1.0207x; 1.0146x over previous
//
#include <hip/hip_runtime.h>

typedef _Float16 f16;
typedef _Float16 f16x2 __attribute__((ext_vector_type(2)));
typedef _Float16 f16x8 __attribute__((ext_vector_type(8)));
typedef float f32x4 __attribute__((ext_vector_type(4)));
typedef unsigned int u32;
typedef u32 u32x16 __attribute__((ext_vector_type(16)));

#define SEQ   512
#define BATCH 256
#define INS   58
#define INP   64          // padded input width
#define HID   256
#define NCAT  18
#define G3    (3*HID)     // 768
#define TC    128         // timestep chunk
#define NCHUNK (SEQ/TC)   // 4
#define MC    (TC*BATCH)  // 32768 rows per chunk
#define HPAD  8           // f16 pad between K-halves (272B -> +4 banks)
#define HLD   (HID + HPAD)

// ---------------------------------------------------------------- dot2 helper
__device__ __forceinline__ float fdot2f(u32 a, u32 b, float c) {
#if __has_builtin(__builtin_amdgcn_fdot2)
  return __builtin_amdgcn_fdot2(__builtin_bit_cast(f16x2, a),
                                __builtin_bit_cast(f16x2, b), c, false);
#else
  f16x2 av = __builtin_bit_cast(f16x2, a);
  f16x2 bv = __builtin_bit_cast(f16x2, b);
  return c + (float)av[0] * (float)bv[0] + (float)av[1] * (float)bv[1];
#endif
}

// ------------------------------------------------------- f32 -> f16 (pad cols)
__global__ void k_convert_pad(const float* __restrict__ src, f16* __restrict__ dst,
                              int rows, int scols, int dcols) {
  int i = blockIdx.x * blockDim.x + threadIdx.x;
  int total = rows * dcols;
  if (i >= total) return;
  int r = i / dcols, c = i - r * dcols;
  float v = (c < scols) ? src[(size_t)r * scols + c] : 0.f;
  dst[i] = (f16)v;
}

// --------------------------------------------------------------- f16 MFMA GEMM
// out[M][768] = A[M][K] * W[768][K]^T + bias.  128x128 tile, BK=32, 4 waves.
#define BM 128
#define BN 128
#define BK 32
#define LDP 40   // padded LDS pitch (f16 elems)

__global__ __launch_bounds__(256, 2)
void k_gemm_f16(const f16* __restrict__ A, const f16* __restrict__ W,
                const float* __restrict__ bias, f16* __restrict__ out,
                int K) {
  __shared__ __align__(16) f16 As[BM][LDP];
  __shared__ __align__(16) f16 Ws[BN][LDP];
  const int tid  = threadIdx.x;
  const int lane = tid & 63;
  const int wave = tid >> 6;            // 0..3
  const int wm = wave >> 1, wn = wave & 1;
  const int n0 = blockIdx.x * BN;       // grid.x = 6
  const int m0 = blockIdx.y * BM;       // grid.y = MC/BM

  f32x4 acc[4][4] = {};

  for (int k0 = 0; k0 < K; k0 += BK) {
    __syncthreads();
#pragma unroll
    for (int c = 0; c < 2; ++c) {
      int j   = c * 256 + tid;          // 0..511
      int row = j >> 2;                 // 0..127
      int kc  = j & 3;                  // 16B chunk within 32-col row
      uint4 va = *(const uint4*)(A + (size_t)(m0 + row) * K + k0 + kc * 8);
      *(uint4*)(&As[row][kc * 8]) = va;
      uint4 vw = *(const uint4*)(W + (size_t)(n0 + row) * K + k0 + kc * 8);
      *(uint4*)(&Ws[row][kc * 8]) = vw;
    }
    __syncthreads();
    const int rsel = lane & 15;
    const int ks   = (lane >> 4) * 8;
    f16x8 af[4], bf[4];
#pragma unroll
    for (int i = 0; i < 4; ++i)
      af[i] = *(const f16x8*)(&As[wm * 64 + i * 16 + rsel][ks]);
#pragma unroll
    for (int j = 0; j < 4; ++j)
      bf[j] = *(const f16x8*)(&Ws[wn * 64 + j * 16 + rsel][ks]);
#pragma unroll
    for (int i = 0; i < 4; ++i)
#pragma unroll
      for (int j = 0; j < 4; ++j)
        acc[i][j] = __builtin_amdgcn_mfma_f32_16x16x32_f16(af[i], bf[j], acc[i][j], 0, 0, 0);
  }

#pragma unroll
  for (int j = 0; j < 4; ++j) {
    int col = n0 + wn * 64 + j * 16 + (lane & 15);
    float bv = bias[col];
#pragma unroll
    for (int i = 0; i < 4; ++i) {
      int rbase = m0 + wm * 64 + i * 16 + ((lane >> 4) << 2);
#pragma unroll
      for (int rr = 0; rr < 4; ++rr)
        out[(size_t)(rbase + rr) * G3 + col] = (f16)(acc[i][j][rr] + bv);
    }
  }
}

// ------------------------------------------------------ persistent GRU layer
// One workgroup (512 threads) per batch element. Thread pair (2r, 2r+1) owns
// hidden unit r: even lane K-cols [0,128), odd [128,256), gate rows
// {r, 256+r, 512+r}. Weights live in 12 INDIVIDUALLY-NAMED 512-bit vectors
// (192 VGPRs) -- no array, so no scratch demotion (rule: runtime-indexed
// ext_vector ARRAYS go to scratch; named scalars with literal subscripts
// cannot). One 12-operand asm pin per iteration keeps them asm-carried.
#define LDV16(dst, p) do {                                                   \
    uint4 t0 = *(const uint4*)((p));      uint4 t1 = *(const uint4*)((p)+8); \
    uint4 t2 = *(const uint4*)((p)+16);   uint4 t3 = *(const uint4*)((p)+24);\
    dst[0]=t0.x; dst[1]=t0.y; dst[2]=t0.z; dst[3]=t0.w;                      \
    dst[4]=t1.x; dst[5]=t1.y; dst[6]=t1.z; dst[7]=t1.w;                      \
    dst[8]=t2.x; dst[9]=t2.y; dst[10]=t2.z; dst[11]=t2.w;                    \
    dst[12]=t3.x; dst[13]=t3.y; dst[14]=t3.z; dst[15]=t3.w;                  \
  } while (0)

#define DOT16(WA, WB, WC, H0, H1, H2, H3) do {                               \
    ar=fdot2f(WA[0],H0.x,ar);  az=fdot2f(WB[0],H0.x,az);  an=fdot2f(WC[0],H0.x,an);  \
    ar=fdot2f(WA[1],H0.y,ar);  az=fdot2f(WB[1],H0.y,az);  an=fdot2f(WC[1],H0.y,an);  \
    ar=fdot2f(WA[2],H0.z,ar);  az=fdot2f(WB[2],H0.z,az);  an=fdot2f(WC[2],H0.z,an);  \
    ar=fdot2f(WA[3],H0.w,ar);  az=fdot2f(WB[3],H0.w,az);  an=fdot2f(WC[3],H0.w,an);  \
    ar=fdot2f(WA[4],H1.x,ar);  az=fdot2f(WB[4],H1.x,az);  an=fdot2f(WC[4],H1.x,an);  \
    ar=fdot2f(WA[5],H1.y,ar);  az=fdot2f(WB[5],H1.y,az);  an=fdot2f(WC[5],H1.y,an);  \
    ar=fdot2f(WA[6],H1.z,ar);  az=fdot2f(WB[6],H1.z,az);  an=fdot2f(WC[6],H1.z,an);  \
    ar=fdot2f(WA[7],H1.w,ar);  az=fdot2f(WB[7],H1.w,az);  an=fdot2f(WC[7],H1.w,an);  \
    ar=fdot2f(WA[8],H2.x,ar);  az=fdot2f(WB[8],H2.x,az);  an=fdot2f(WC[8],H2.x,an);  \
    ar=fdot2f(WA[9],H2.y,ar);  az=fdot2f(WB[9],H2.y,az);  an=fdot2f(WC[9],H2.y,an);  \
    ar=fdot2f(WA[10],H2.z,ar); az=fdot2f(WB[10],H2.z,az); an=fdot2f(WC[10],H2.z,an); \
    ar=fdot2f(WA[11],H2.w,ar); az=fdot2f(WB[11],H2.w,az); an=fdot2f(WC[11],H2.w,an); \
    ar=fdot2f(WA[12],H3.x,ar); az=fdot2f(WB[12],H3.x,az); an=fdot2f(WC[12],H3.x,an); \
    ar=fdot2f(WA[13],H3.y,ar); az=fdot2f(WB[13],H3.y,az); an=fdot2f(WC[13],H3.y,an); \
    ar=fdot2f(WA[14],H3.z,ar); az=fdot2f(WB[14],H3.z,az); an=fdot2f(WC[14],H3.z,an); \
    ar=fdot2f(WA[15],H3.w,ar); az=fdot2f(WB[15],H3.w,az); an=fdot2f(WC[15],H3.w,an); \
  } while (0)

#define PIN_W() asm volatile(""                                              \
    : "+v"(wA0), "+v"(wA1), "+v"(wA2), "+v"(wA3),                            \
      "+v"(wB0), "+v"(wB1), "+v"(wB2), "+v"(wB3),                            \
      "+v"(wC0), "+v"(wC1), "+v"(wC2), "+v"(wC3))

template <int FINAL>
__global__ __attribute__((amdgpu_flat_work_group_size(512, 512),
                          amdgpu_waves_per_eu(2, 2)))
void k_gru(const f16* __restrict__ gx,     // [MC][768], includes b_ih
           const f16* __restrict__ Whh,    // [768][256] f16
           const float* __restrict__ bhh,  // [768]
           f16* __restrict__ hout,         // [MC][256]   (FINAL==0)
           float* __restrict__ hstate,     // [BATCH][256] f32 carry
           int first, int last,
           const float* __restrict__ fcw,  // [18][256]  (FINAL only)
           const float* __restrict__ fcb,  // [18]
           float* __restrict__ out) {      // [256][18]
  const int b   = blockIdx.x;
  const int tid = threadIdx.x;
  const int r   = tid >> 1;   // hidden index 0..255
  const int kh  = tid & 1;    // K half

  __shared__ __align__(16) f16 hsh[2][HLD];
  __shared__ float red[HID];
  __shared__ float red2[NCAT * 16];

  // ---- load recurrent weights into 12 NAMED 512-bit register vectors ----
  u32x16 wA0, wA1, wA2, wA3, wB0, wB1, wB2, wB3, wC0, wC1, wC2, wC3;
  {
    const f16* pA = Whh + (size_t)(0 * HID + r) * HID + kh * 128;
    const f16* pB = Whh + (size_t)(1 * HID + r) * HID + kh * 128;
    const f16* pC = Whh + (size_t)(2 * HID + r) * HID + kh * 128;
    LDV16(wA0, pA);       LDV16(wA1, pA + 32);
    LDV16(wA2, pA + 64);  LDV16(wA3, pA + 96);
    LDV16(wB0, pB);       LDV16(wB1, pB + 32);
    LDV16(wB2, pB + 64);  LDV16(wB3, pB + 96);
    LDV16(wC0, pC);       LDV16(wC1, pC + 32);
    LDV16(wC2, pC + 64);  LDV16(wC3, pC + 96);
  }
  PIN_W();   // 192 VGPRs simultaneously live here

  float bhr = 0.f, bhz = 0.f, bhn = 0.f;
  float hprev = 0.f;
  if (kh == 0) {
    bhr = bhh[r]; bhz = bhh[HID + r]; bhn = bhh[2 * HID + r];
    hprev = first ? 0.f : hstate[(size_t)b * HID + r];
    hsh[0][r + (r >= 128 ? HPAD : 0)] = (f16)hprev;
  }

  // prefetch gx for t=0
  float gxr = 0.f, gxz = 0.f, gxn = 0.f;
  if (kh == 0) {
    const f16* g0 = gx + ((size_t)0 * BATCH + b) * G3;
    gxr = (float)g0[r]; gxz = (float)g0[HID + r]; gxn = (float)g0[2 * HID + r];
  }
  __syncthreads();

  int cur = 0;
  for (int t = 0; t < TC; ++t) {
    PIN_W();   // asm-carried across iterations: cannot be remat'd or dropped

    // prefetch next timestep's gx (consumed after the dot phase)
    float nxr = 0.f, nxz = 0.f, nxn = 0.f;
    if (kh == 0 && t + 1 < TC) {
      const f16* gn = gx + ((size_t)(t + 1) * BATCH + b) * G3;
      nxr = (float)gn[r]; nxz = (float)gn[HID + r]; nxn = (float)gn[2 * HID + r];
    }

    // ---- dot phase over this lane's K half (broadcast reads, padded) ----
    float ar = 0.f, az = 0.f, an = 0.f;
    const uint4* hp = (const uint4*)(&hsh[cur][kh * (128 + HPAD)]);
    {
      uint4 h0 = hp[0], h1 = hp[1], h2 = hp[2], h3 = hp[3];
      DOT16(wA0, wB0, wC0, h0, h1, h2, h3);
      h0 = hp[4]; h1 = hp[5]; h2 = hp[6]; h3 = hp[7];
      DOT16(wA1, wB1, wC1, h0, h1, h2, h3);
      h0 = hp[8]; h1 = hp[9]; h2 = hp[10]; h3 = hp[11];
      DOT16(wA2, wB2, wC2, h0, h1, h2, h3);
      h0 = hp[12]; h1 = hp[13]; h2 = hp[14]; h3 = hp[15];
      DOT16(wA3, wB3, wC3, h0, h1, h2, h3);
    }
    // merge K halves within the lane pair (same wave -> no barrier)
    ar += __shfl_xor(ar, 1);
    az += __shfl_xor(az, 1);
    an += __shfl_xor(an, 1);

    if (kh == 0) {
      float ghr = ar + bhr;
      float ghz = az + bhz;
      float ghn = an + bhn;
      float rg = 1.f / (1.f + __expf(-(gxr + ghr)));
      float zg = 1.f / (1.f + __expf(-(gxz + ghz)));
      float nt = gxn + rg * ghn;
      float e2 = __expf(-2.f * fabsf(nt));       // safe tanh
      float th = (1.f - e2) / (1.f + e2);
      float ng = (nt >= 0.f) ? th : -th;
      float hn = (1.f - zg) * ng + zg * hprev;
      hprev = hn;
      hsh[cur ^ 1][r + (r >= 128 ? HPAD : 0)] = (f16)hn;  // other buffer
      if (!FINAL) hout[((size_t)t * BATCH + b) * HID + r] = (f16)hn;
      gxr = nxr; gxz = nxz; gxn = nxn;
    }
    __syncthreads();                             // h_new visible to all
    cur ^= 1;
  }

  if (kh == 0) hstate[(size_t)b * HID + r] = hprev;

  if (FINAL) {
    if (last) {
      if (kh == 0) red[r] = hprev;
      __syncthreads();
      int c = tid >> 4, seg = tid & 15;
      if (c < NCAT) {
        const float* wrow = fcw + (size_t)c * HID + seg * 16;
        const float* hseg = red + seg * 16;
        float s = 0.f;
#pragma unroll
        for (int q = 0; q < 16; ++q) s += wrow[q] * hseg[q];
        red2[c * 16 + seg] = s;
      }
      __syncthreads();
      if (tid < NCAT) {
        float s = fcb[tid];
#pragma unroll
        for (int k = 0; k < 16; ++k) s += red2[tid * 16 + k];
        out[(size_t)b * NCAT + tid] = s;
      }
    }
  }
}

// ---------------------------------------------------------------------- launch
extern "C" void kernel_launch(void* const* d_in, const int* in_sizes, int n_in,
                              void* d_out, int out_size, void* d_ws, size_t ws_size,
                              hipStream_t stream) {
  const float* x    = (const float*)d_in[0];
  const float* Wih0 = (const float*)d_in[1];
  const float* Whh0 = (const float*)d_in[2];
  const float* bih0 = (const float*)d_in[3];
  const float* bhh0 = (const float*)d_in[4];
  const float* Wih1 = (const float*)d_in[5];
  const float* Whh1 = (const float*)d_in[6];
  const float* bih1 = (const float*)d_in[7];
  const float* bhh1 = (const float*)d_in[8];
  const float* fcw  = (const float*)d_in[9];
  const float* fcb  = (const float*)d_in[10];
  float* out = (float*)d_out;

  // ---- workspace layout (~73 MB total) ----
  char* ws = (char*)d_ws;
  size_t off = 0;
  f16*   whh0h = (f16*)(ws + off); off += (size_t)G3 * HID * 2;      //   393,216
  f16*   whh1h = (f16*)(ws + off); off += (size_t)G3 * HID * 2;      //   393,216
  f16*   wih0h = (f16*)(ws + off); off += (size_t)G3 * INP * 2;      //    98,304
  f16*   wih1h = (f16*)(ws + off); off += (size_t)G3 * HID * 2;      //   393,216
  float* h0st  = (float*)(ws + off); off += (size_t)BATCH * HID * 4; //   262,144
  float* h1st  = (float*)(ws + off); off += (size_t)BATCH * HID * 4; //   262,144
  f16*   xhc   = (f16*)(ws + off); off += (size_t)MC * INP * 2;      // 4,194,304
  f16*   h0c   = (f16*)(ws + off); off += (size_t)MC * HID * 2;      // 16,777,216
  f16*   gxc   = (f16*)(ws + off); off += (size_t)MC * G3 * 2;       // 50,331,648
  // total ~73.1 MB

  // ---- one-time weight converts ----
  k_convert_pad<<<(G3 * INP + 255) / 256, 256, 0, stream>>>(Wih0, wih0h, G3, INS, INP);
  k_convert_pad<<<(G3 * HID + 255) / 256, 256, 0, stream>>>(Whh0, whh0h, G3, HID, HID);
  k_convert_pad<<<(G3 * HID + 255) / 256, 256, 0, stream>>>(Whh1, whh1h, G3, HID, HID);
  k_convert_pad<<<(G3 * HID + 255) / 256, 256, 0, stream>>>(Wih1, wih1h, G3, HID, HID);

  for (int c = 0; c < NCHUNK; ++c) {
    int first = (c == 0), last = (c == NCHUNK - 1);
    const float* xc = x + (size_t)c * MC * INS;

    // x chunk -> f16, pad 58 -> 64
    k_convert_pad<<<(MC * INP + 255) / 256, 256, 0, stream>>>(xc, xhc, MC, INS, INP);
    // gx0 = xh @ Wih0^T + b_ih0
    k_gemm_f16<<<dim3(G3 / BN, MC / BM), 256, 0, stream>>>(xhc, wih0h, bih0, gxc, INP);
    // layer-0 recurrence over this chunk
    k_gru<0><<<BATCH, 512, 0, stream>>>(gxc, whh0h, bhh0, h0c, h0st, first, last,
                                        nullptr, nullptr, nullptr);
    // gx1 = h0 @ Wih1^T + b_ih1 (reuse gxc; stream order serializes)
    k_gemm_f16<<<dim3(G3 / BN, MC / BM), 256, 0, stream>>>(h0c, wih1h, bih1, gxc, HID);
    // layer-1 recurrence (+ final FC on last chunk)
    k_gru<1><<<BATCH, 512, 0, stream>>>(gxc, whh1h, bhh1, nullptr, h1st, first, last,
                                        fcw, fcb, out);
  }
}